// Round 8
// baseline (216.515 us; speedup 1.0000x reference)
//
#include <hip/hip_runtime.h>
#include <limits.h>
#include <math.h>

#define NSEG 16
#define LMAX 2048   // max LUT entries (8 B each -> 16 KB LDS)

typedef float f32x4 __attribute__((ext_vector_type(4)));
typedef float f32x2 __attribute__((ext_vector_type(2)));

// Exact float epilogue (proven absmax 0.0): t = trunc(x*2^16) exact int in f32;
// u = floor(t*2^-e) == xq>>e; y = fma(s*2^-16, u, b*2^-16) exact.
__device__ __forceinline__ float plac_tail(float t, f32x4 c) {
    float u = floorf(t * c.z);
    return fmaf(c.y, u, c.x);
}

__device__ __forceinline__ float plac_lut_one(float xv, const f32x2* __restrict__ s_lut,
                                              const f32x4* __restrict__ s_tab,
                                              int LOm, int S, int Lm1) {
    float t = truncf(xv * 65536.0f);
    int xq = (int)t;
    int idx = (xq - LOm) >> S;                 // LOm = LO - 2^S (folds the +1)
    idx = min(max(idx, 0), Lm1);
    f32x2 e = s_lut[idx];                      // {bp_next (f32), m (int bits)}
    int m = __float_as_int(e.y);
    int seg = m + (t >= e.x ? 1 : 0);
    return plac_tail(t, s_tab[seg]);
}

__device__ __forceinline__ float plac_full_one(float xv, const float* __restrict__ bpf,
                                               const f32x4* __restrict__ s_tab) {
    float t = truncf(xv * 65536.0f);
    int seg = 0;
    #pragma unroll
    for (int k = 0; k < 15; ++k) seg += (t >= bpf[k]);
    return plac_tail(t, s_tab[seg]);
}

__global__ __launch_bounds__(256) void plac_kernel(
    const float* __restrict__ x,
    const int* __restrict__ bps,        // 15 sorted interior breakpoints (Q16.16)
    const int* __restrict__ intercepts, // 16
    const int* __restrict__ signs,      // 16, in {-1,+1}
    const int* __restrict__ exps,       // 16, in [0,8)
    float* __restrict__ out,
    long long n4, long long n, long long per)  // per = packets per block (slab)
{
    __shared__ f32x2 s_lut[LMAX];
    __shared__ f32x4 s_tab[NSEG];

    const int tid = threadIdx.x;

    // ---- uniform setup ----
    int bp[15];
    #pragma unroll
    for (int k = 0; k < 15; ++k) bp[k] = bps[k];
    int gapmin = INT_MAX;
    #pragma unroll
    for (int k = 0; k < 14; ++k) gapmin = min(gapmin, bp[k + 1] - bp[k]);
    const int LO = bp[0];
    const int range = bp[14] - bp[0];
    int Smin = 0;
    while (((range >> Smin) + 2) > LMAX) ++Smin;
    int S = 0;
    bool valid = false;
    if (gapmin > 0) {
        S = 31 - __clz(gapmin);     // 2^S <= gapmin => <=1 breakpoint per bucket
        valid = (S >= Smin);
    }
    const int L   = (range >> S) + 2;
    const int Lm1 = L - 1;
    const int LOm = LO - (1 << S);

    if (tid < NSEG) {
        float b  = (float)intercepts[tid] * (1.0f / 65536.0f);
        float s  = (float)signs[tid]      * (1.0f / 65536.0f);
        float ei = __int_as_float((127 - exps[tid]) << 23);
        f32x4 row = {b, s, ei, 0.0f};
        s_tab[tid] = row;
    }
    if (valid) {
        for (int i = tid; i < L; i += 256) {
            int m = 0;
            float bpn = INFINITY;
            if (i > 0) {
                int left = LO + ((i - 1) << S);
                #pragma unroll
                for (int k = 14; k >= 0; --k) {
                    if (bp[k] <= left) m += 1;
                    else               bpn = (float)bp[k];
                }
            } else {
                bpn = (float)bp[0];
            }
            f32x2 e = {bpn, __int_as_float(m)};
            s_lut[i] = e;
        }
    }
    __syncthreads();

    const f32x4* __restrict__ x4 = (const f32x4*)x;
    f32x4* __restrict__ o4 = (f32x4*)out;

    // ---- block-owned contiguous slab, 512 packets (8 KB) per step ----
    long long start = (long long)blockIdx.x * per;
    long long end   = start + per;
    if (end > n4) end = n4;

    if (valid) {
        long long p = start;
        if (p + 512 <= end) {
            // Prime: iteration-0 packets.
            f32x4 v0 = x4[p + tid];
            f32x4 v1 = x4[p + 256 + tid];
            // Steady state: prefetch iter k+1 BEFORE compute/store of iter k,
            // so each wave always has reads in flight.
            for (; p + 1024 <= end; p += 512) {
                f32x4 u0 = x4[p + 512 + tid];
                f32x4 u1 = x4[p + 768 + tid];
                f32x4 r0, r1;
                #pragma unroll
                for (int j = 0; j < 4; ++j) r0[j] = plac_lut_one(v0[j], s_lut, s_tab, LOm, S, Lm1);
                #pragma unroll
                for (int j = 0; j < 4; ++j) r1[j] = plac_lut_one(v1[j], s_lut, s_tab, LOm, S, Lm1);
                o4[p + tid]       = r0;
                o4[p + 256 + tid] = r1;
                v0 = u0;
                v1 = u1;
            }
            // Drain the primed/prefetched pair.
            {
                f32x4 r0, r1;
                #pragma unroll
                for (int j = 0; j < 4; ++j) r0[j] = plac_lut_one(v0[j], s_lut, s_tab, LOm, S, Lm1);
                #pragma unroll
                for (int j = 0; j < 4; ++j) r1[j] = plac_lut_one(v1[j], s_lut, s_tab, LOm, S, Lm1);
                o4[p + tid]       = r0;
                o4[p + 256 + tid] = r1;
                p += 512;
            }
        }
        // Slab remainder (< 512 packets).
        for (long long i = p + tid; i < end; i += 256) {
            f32x4 v = x4[i];
            f32x4 r;
            #pragma unroll
            for (int j = 0; j < 4; ++j) r[j] = plac_lut_one(v[j], s_lut, s_tab, LOm, S, Lm1);
            o4[i] = r;
        }
        if (blockIdx.x == 0) {
            for (long long ii = n4 * 4 + tid; ii < n; ii += 256)
                out[ii] = plac_lut_one(x[ii], s_lut, s_tab, LOm, S, Lm1);
        }
    } else {
        // Fallback (tiny/duplicate breakpoint gaps): full 15-compare path.
        float bpf[15];
        #pragma unroll
        for (int k = 0; k < 15; ++k) bpf[k] = (float)bp[k];
        for (long long i = start + tid; i < end; i += 256) {
            f32x4 v = x4[i];
            f32x4 r;
            #pragma unroll
            for (int j = 0; j < 4; ++j) r[j] = plac_full_one(v[j], bpf, s_tab);
            o4[i] = r;
        }
        if (blockIdx.x == 0) {
            for (long long ii = n4 * 4 + tid; ii < n; ii += 256)
                out[ii] = plac_full_one(x[ii], bpf, s_tab);
        }
    }
}

extern "C" void kernel_launch(void* const* d_in, const int* in_sizes, int n_in,
                              void* d_out, int out_size, void* d_ws, size_t ws_size,
                              hipStream_t stream) {
    const float* x          = (const float*)d_in[0];
    const int*   bps        = (const int*)d_in[1];
    const int*   intercepts = (const int*)d_in[2];
    const int*   signs      = (const int*)d_in[3];
    const int*   exps       = (const int*)d_in[4];
    float* out = (float*)d_out;

    long long n  = (long long)out_size;
    long long n4 = n / 4;

    const int grid = 1024;  // 4 blocks/CU, 16 waves/CU: 2x in-flight reads vs r6
    long long per = (n4 + grid - 1) / grid;

    plac_kernel<<<grid, 256, 0, stream>>>(x, bps, intercepts, signs, exps,
                                          out, n4, n, per);
}

// Round 9
// 205.891 us; speedup vs baseline: 1.0516x; 1.0516x over previous
//
#include <hip/hip_runtime.h>
#include <limits.h>
#include <math.h>

#define NSEG 16
#define LMAX 2048   // max LUT entries (8 B each -> 16 KB LDS)

typedef float f32x4 __attribute__((ext_vector_type(4)));
typedef float f32x2 __attribute__((ext_vector_type(2)));

// Exact float epilogue (proven absmax 0.0): t = trunc(x*2^16) exact int in f32;
// u = floor(t*2^-e) == xq>>e; y = fma(s*2^-16, u, b*2^-16) exact.
__device__ __forceinline__ float plac_tail(float t, f32x4 c) {
    float u = floorf(t * c.z);
    return fmaf(c.y, u, c.x);
}

__device__ __forceinline__ float plac_lut_one(float xv, const f32x2* __restrict__ s_lut,
                                              const f32x4* __restrict__ s_tab,
                                              int LOm, int S, int Lm1) {
    float t = truncf(xv * 65536.0f);
    int xq = (int)t;
    int idx = (xq - LOm) >> S;                 // LOm = LO - 2^S (folds the +1)
    idx = min(max(idx, 0), Lm1);
    f32x2 e = s_lut[idx];                      // {bp_next (f32), m (int bits)}
    int m = __float_as_int(e.y);
    int seg = m + (t >= e.x ? 1 : 0);
    return plac_tail(t, s_tab[seg]);
}

__device__ __forceinline__ float plac_full_one(float xv, const float* __restrict__ bpf,
                                               const f32x4* __restrict__ s_tab) {
    float t = truncf(xv * 65536.0f);
    int seg = 0;
    #pragma unroll
    for (int k = 0; k < 15; ++k) seg += (t >= bpf[k]);
    return plac_tail(t, s_tab[seg]);
}

__global__ __launch_bounds__(256) void plac_kernel(
    const float* __restrict__ x,
    const int* __restrict__ bps,        // 15 sorted interior breakpoints (Q16.16)
    const int* __restrict__ intercepts, // 16
    const int* __restrict__ signs,      // 16, in {-1,+1}
    const int* __restrict__ exps,       // 16, in [0,8)
    float* __restrict__ out,
    long long n4, long long n, long long per)  // per = packets per block (slab)
{
    __shared__ f32x2 s_lut[LMAX];
    __shared__ f32x4 s_tab[NSEG];

    const int tid = threadIdx.x;

    // ---- uniform setup ----
    int bp[15];
    #pragma unroll
    for (int k = 0; k < 15; ++k) bp[k] = bps[k];
    int gapmin = INT_MAX;
    #pragma unroll
    for (int k = 0; k < 14; ++k) gapmin = min(gapmin, bp[k + 1] - bp[k]);
    const int LO = bp[0];
    const int range = bp[14] - bp[0];
    int Smin = 0;
    while (((range >> Smin) + 2) > LMAX) ++Smin;
    int S = 0;
    bool valid = false;
    if (gapmin > 0) {
        S = 31 - __clz(gapmin);     // 2^S <= gapmin => <=1 breakpoint per bucket
        valid = (S >= Smin);
    }
    const int L   = (range >> S) + 2;
    const int Lm1 = L - 1;
    const int LOm = LO - (1 << S);

    if (tid < NSEG) {
        float b  = (float)intercepts[tid] * (1.0f / 65536.0f);
        float s  = (float)signs[tid]      * (1.0f / 65536.0f);
        float ei = __int_as_float((127 - exps[tid]) << 23);
        f32x4 row = {b, s, ei, 0.0f};
        s_tab[tid] = row;
    }
    if (valid) {
        for (int i = tid; i < L; i += 256) {
            int m = 0;
            float bpn = INFINITY;
            if (i > 0) {
                int left = LO + ((i - 1) << S);
                #pragma unroll
                for (int k = 14; k >= 0; --k) {
                    if (bp[k] <= left) m += 1;
                    else               bpn = (float)bp[k];
                }
            } else {
                bpn = (float)bp[0];
            }
            f32x2 e = {bpn, __int_as_float(m)};
            s_lut[i] = e;
        }
    }
    __syncthreads();

    const f32x4* __restrict__ x4 = (const f32x4*)x;
    f32x4* __restrict__ o4 = (f32x4*)out;

    // ---- block-owned contiguous slab, 512 packets (8 KB) per step ----
    long long start = (long long)blockIdx.x * per;
    long long end   = start + per;
    if (end > n4) end = n4;

    if (valid) {
        long long p = start;
        if (p + 1024 <= end) {
            // Prime: iterations 0 and 1 (2-deep pipeline -> 3 KB reads in
            // flight per wave; covers HBM latency during compute/store).
            f32x4 v0 = x4[p + tid];
            f32x4 v1 = x4[p + 256 + tid];
            f32x4 u0 = x4[p + 512 + tid];
            f32x4 u1 = x4[p + 768 + tid];
            for (; p + 1536 <= end; p += 512) {
                f32x4 w0 = x4[p + 1024 + tid];
                f32x4 w1 = x4[p + 1280 + tid];
                f32x4 r0, r1;
                #pragma unroll
                for (int j = 0; j < 4; ++j) r0[j] = plac_lut_one(v0[j], s_lut, s_tab, LOm, S, Lm1);
                #pragma unroll
                for (int j = 0; j < 4; ++j) r1[j] = plac_lut_one(v1[j], s_lut, s_tab, LOm, S, Lm1);
                o4[p + tid]       = r0;
                o4[p + 256 + tid] = r1;
                v0 = u0; v1 = u1;
                u0 = w0; u1 = w1;
            }
            // Drain the two in-flight pairs.
            #pragma unroll
            for (int d = 0; d < 2; ++d) {
                f32x4 r0, r1;
                #pragma unroll
                for (int j = 0; j < 4; ++j) r0[j] = plac_lut_one(v0[j], s_lut, s_tab, LOm, S, Lm1);
                #pragma unroll
                for (int j = 0; j < 4; ++j) r1[j] = plac_lut_one(v1[j], s_lut, s_tab, LOm, S, Lm1);
                o4[p + tid]       = r0;
                o4[p + 256 + tid] = r1;
                v0 = u0; v1 = u1;
                p += 512;
            }
        } else if (p + 512 <= end) {
            f32x4 v0 = x4[p + tid];
            f32x4 v1 = x4[p + 256 + tid];
            f32x4 r0, r1;
            #pragma unroll
            for (int j = 0; j < 4; ++j) r0[j] = plac_lut_one(v0[j], s_lut, s_tab, LOm, S, Lm1);
            #pragma unroll
            for (int j = 0; j < 4; ++j) r1[j] = plac_lut_one(v1[j], s_lut, s_tab, LOm, S, Lm1);
            o4[p + tid]       = r0;
            o4[p + 256 + tid] = r1;
            p += 512;
        }
        // Slab remainder (< 512 packets).
        for (long long i = p + tid; i < end; i += 256) {
            f32x4 v = x4[i];
            f32x4 r;
            #pragma unroll
            for (int j = 0; j < 4; ++j) r[j] = plac_lut_one(v[j], s_lut, s_tab, LOm, S, Lm1);
            o4[i] = r;
        }
        if (blockIdx.x == 0) {
            for (long long ii = n4 * 4 + tid; ii < n; ii += 256)
                out[ii] = plac_lut_one(x[ii], s_lut, s_tab, LOm, S, Lm1);
        }
    } else {
        // Fallback (tiny/duplicate breakpoint gaps): full 15-compare path.
        float bpf[15];
        #pragma unroll
        for (int k = 0; k < 15; ++k) bpf[k] = (float)bp[k];
        for (long long i = start + tid; i < end; i += 256) {
            f32x4 v = x4[i];
            f32x4 r;
            #pragma unroll
            for (int j = 0; j < 4; ++j) r[j] = plac_full_one(v[j], bpf, s_tab);
            o4[i] = r;
        }
        if (blockIdx.x == 0) {
            for (long long ii = n4 * 4 + tid; ii < n; ii += 256)
                out[ii] = plac_full_one(x[ii], bpf, s_tab);
        }
    }
}

extern "C" void kernel_launch(void* const* d_in, const int* in_sizes, int n_in,
                              void* d_out, int out_size, void* d_ws, size_t ws_size,
                              hipStream_t stream) {
    const float* x          = (const float*)d_in[0];
    const int*   bps        = (const int*)d_in[1];
    const int*   intercepts = (const int*)d_in[2];
    const int*   signs      = (const int*)d_in[3];
    const int*   exps       = (const int*)d_in[4];
    float* out = (float*)d_out;

    long long n  = (long long)out_size;
    long long n4 = n / 4;

    const int grid = 512;   // 2 blocks/CU: best stream-locality point (r6-r8)
    long long per = (n4 + grid - 1) / grid;

    plac_kernel<<<grid, 256, 0, stream>>>(x, bps, intercepts, signs, exps,
                                          out, n4, n, per);
}